// Round 2
// baseline (710.812 us; speedup 1.0000x reference)
//
#include <hip/hip_runtime.h>

#define N_SEQ 4140
#define C_IN 256
#define HEADS 8
#define DK 32
#define NTILES 33          // ceil(4140/128)

// ---------------------------------------------------------------------------
// QKV: q/k/v[kc][n] = sum_c w[kc][c] * x[c][n] + b[kc]
// grid: (ceil(N/256), 96) ; blockIdx.y*8 selects 8 output channels in [0,768)
// ---------------------------------------------------------------------------
__global__ __launch_bounds__(256) void qkv_kernel(
    const float* __restrict__ x,
    const float* __restrict__ q_w, const float* __restrict__ q_b,
    const float* __restrict__ k_w, const float* __restrict__ k_b,
    const float* __restrict__ v_w, const float* __restrict__ v_b,
    float* __restrict__ qkv)
{
    const int n = blockIdx.x * 256 + threadIdx.x;
    const int cc0 = blockIdx.y * 8;
    const int mat = cc0 >> 8;          // 0=q, 1=k, 2=v
    const int row0 = cc0 & 255;
    const float* w; const float* b;
    if (mat == 0)      { w = q_w; b = q_b; }
    else if (mat == 1) { w = k_w; b = k_b; }
    else               { w = v_w; b = v_b; }
    if (n >= N_SEQ) return;

    float acc[8];
#pragma unroll
    for (int j = 0; j < 8; ++j) acc[j] = b[row0 + j];
    const float* wr = w + (size_t)row0 * C_IN;
    for (int c = 0; c < C_IN; ++c) {
        const float xv = x[(size_t)c * N_SEQ + n];
#pragma unroll
        for (int j = 0; j < 8; ++j)
            acc[j] = fmaf(wr[j * C_IN + c], xv, acc[j]);
    }
    float* out = qkv + (size_t)mat * C_IN * N_SEQ;
#pragma unroll
    for (int j = 0; j < 8; ++j)
        out[(size_t)(row0 + j) * N_SEQ + n] = acc[j];
}

// ---------------------------------------------------------------------------
// Flash attention (f32). 128 threads/block; each thread owns 2 query rows
// (n0+tid, n0+128+tid). K/V tiles of 128 keys staged in LDS (pad 36 -> 16B
// aligned rows, broadcast reads). Keys split across blockIdx.z; partials
// (m, l, acc[32]) per query per split written to workspace.
// grid: (ceil(N/256), HEADS, nz)
// ---------------------------------------------------------------------------
__global__ __launch_bounds__(128, 1) void attn_kernel(
    const float* __restrict__ qkv, const float* __restrict__ log_qw,
    float* __restrict__ pm, float* __restrict__ pl, float* __restrict__ pacc,
    int tiles_per_z)
{
    __shared__ float kt[128][36];
    __shared__ float vt[128][36];
    __shared__ float lw[128];

    const int tid = threadIdx.x;
    const int h = blockIdx.y;
    const int z = blockIdx.z;
    const int n0 = blockIdx.x * 256;

    const float* q = qkv;
    const float* k = qkv + (size_t)C_IN * N_SEQ;
    const float* v = qkv + 2 * (size_t)C_IN * N_SEQ;

    const int nq0 = n0 + tid;
    const int nq1 = n0 + 128 + tid;
    const bool valid0 = nq0 < N_SEQ;
    const bool valid1 = nq1 < N_SEQ;

    float qr[2][32], acc[2][32];
    float m_run[2] = { -1e30f, -1e30f };
    float l_run[2] = { 0.f, 0.f };
#pragma unroll
    for (int d = 0; d < 32; ++d) {
        qr[0][d] = valid0 ? q[(size_t)(h * 32 + d) * N_SEQ + nq0] : 0.f;
        qr[1][d] = valid1 ? q[(size_t)(h * 32 + d) * N_SEQ + nq1] : 0.f;
        acc[0][d] = 0.f;
        acc[1][d] = 0.f;
    }

    const float scale = 0.17677669529663687f;  // 1/sqrt(32)
    const int t0 = z * tiles_per_z;
    const int t1 = min(NTILES, t0 + tiles_per_z);

    for (int t = t0; t < t1; ++t) {
        const int m0 = t * 128;
        __syncthreads();
        {
            const int gm = m0 + tid;
            const bool ok = gm < N_SEQ;
#pragma unroll
            for (int p = 0; p < 32; ++p) {
                kt[tid][p] = ok ? k[(size_t)(h * 32 + p) * N_SEQ + gm] : 0.f;
                vt[tid][p] = ok ? v[(size_t)(h * 32 + p) * N_SEQ + gm] : 0.f;
            }
            lw[tid] = ok ? log_qw[gm] : -__builtin_inff();
        }
        __syncthreads();

        for (int ch = 0; ch < 16; ++ch) {
            float s[2][8];
#pragma unroll
            for (int j = 0; j < 8; ++j) {
                const int mm = ch * 8 + j;
                float d0 = 0.f, d1 = 0.f;
#pragma unroll
                for (int d = 0; d < 32; ++d) {
                    const float kv = kt[mm][d];
                    d0 = fmaf(qr[0][d], kv, d0);
                    d1 = fmaf(qr[1][d], kv, d1);
                }
                const float lwv = lw[mm];
                s[0][j] = fmaf(d0, scale, lwv);
                s[1][j] = fmaf(d1, scale, lwv);
            }
            float pexp[2][8];
#pragma unroll
            for (int u = 0; u < 2; ++u) {
                float cmax = s[u][0];
#pragma unroll
                for (int j = 1; j < 8; ++j) cmax = fmaxf(cmax, s[u][j]);
                const float mnew = fmaxf(m_run[u], cmax);
                const float esc = __expf(m_run[u] - mnew);
                m_run[u] = mnew;
                l_run[u] *= esc;
#pragma unroll
                for (int d = 0; d < 32; ++d) acc[u][d] *= esc;
#pragma unroll
                for (int j = 0; j < 8; ++j) {
                    pexp[u][j] = __expf(s[u][j] - mnew);
                    l_run[u] += pexp[u][j];
                }
            }
#pragma unroll
            for (int j = 0; j < 8; ++j) {
                const int mm = ch * 8 + j;
#pragma unroll
                for (int d = 0; d < 32; ++d) {
                    const float vv = vt[mm][d];
                    acc[0][d] = fmaf(pexp[0][j], vv, acc[0][d]);
                    acc[1][d] = fmaf(pexp[1][j], vv, acc[1][d]);
                }
            }
        }
    }

    const size_t HN = (size_t)HEADS * N_SEQ;
    if (valid0) {
        const size_t qi = (size_t)h * N_SEQ + nq0;
        pm[z * HN + qi] = m_run[0];
        pl[z * HN + qi] = l_run[0];
        float* pa = pacc + (z * HN + qi) * 32;
#pragma unroll
        for (int d = 0; d < 32; ++d) pa[d] = acc[0][d];
    }
    if (valid1) {
        const size_t qi = (size_t)h * N_SEQ + nq1;
        pm[z * HN + qi] = m_run[1];
        pl[z * HN + qi] = l_run[1];
        float* pa = pacc + (z * HN + qi) * 32;
#pragma unroll
        for (int d = 0; d < 32; ++d) pa[d] = acc[1][d];
    }
}

// ---------------------------------------------------------------------------
// Merge key-split partials -> attn_out[c][n] (channel-major)
// ---------------------------------------------------------------------------
__global__ __launch_bounds__(256) void merge_kernel(
    const float* __restrict__ pm, const float* __restrict__ pl,
    const float* __restrict__ pacc, float* __restrict__ attn_out, int nz)
{
    const int idx = blockIdx.x * 256 + threadIdx.x;
    const size_t HN = (size_t)HEADS * N_SEQ;
    if (idx >= (int)HN) return;
    const int h = idx / N_SEQ;
    const int n = idx - h * N_SEQ;

    float mg = pm[idx];
    for (int zz = 1; zz < nz; ++zz) mg = fmaxf(mg, pm[zz * HN + idx]);

    float lg = 0.f;
    float acc[32];
#pragma unroll
    for (int d = 0; d < 32; ++d) acc[d] = 0.f;
    for (int zz = 0; zz < nz; ++zz) {
        const float e = __expf(pm[zz * HN + idx] - mg);
        lg += pl[zz * HN + idx] * e;
        const float* pa = pacc + (zz * HN + idx) * 32;
#pragma unroll
        for (int d = 0; d < 32; ++d) acc[d] = fmaf(pa[d], e, acc[d]);
    }
    const float inv = 1.0f / lg;
#pragma unroll
    for (int d = 0; d < 32; ++d)
        attn_out[(size_t)(h * 32 + d) * N_SEQ + n] = acc[d] * inv;
}

// ---------------------------------------------------------------------------
// Proj: out[k][n] = sum_c p_w[k][c] * attn_out[c][n] + p_b[k]
// ---------------------------------------------------------------------------
__global__ __launch_bounds__(256) void proj_kernel(
    const float* __restrict__ x, const float* __restrict__ p_w,
    const float* __restrict__ p_b, float* __restrict__ out)
{
    const int n = blockIdx.x * 256 + threadIdx.x;
    const int row0 = blockIdx.y * 8;
    if (n >= N_SEQ) return;
    float acc[8];
#pragma unroll
    for (int j = 0; j < 8; ++j) acc[j] = p_b[row0 + j];
    const float* wr = p_w + (size_t)row0 * C_IN;
    for (int c = 0; c < C_IN; ++c) {
        const float xv = x[(size_t)c * N_SEQ + n];
#pragma unroll
        for (int j = 0; j < 8; ++j)
            acc[j] = fmaf(wr[j * C_IN + c], xv, acc[j]);
    }
#pragma unroll
    for (int j = 0; j < 8; ++j)
        out[(size_t)(row0 + j) * N_SEQ + n] = acc[j];
}

extern "C" void kernel_launch(void* const* d_in, const int* in_sizes, int n_in,
                              void* d_out, int out_size, void* d_ws, size_t ws_size,
                              hipStream_t stream) {
    const float* query  = (const float*)d_in[0];
    const float* q_w    = (const float*)d_in[1];
    const float* q_b    = (const float*)d_in[2];
    const float* k_w    = (const float*)d_in[3];
    const float* k_b    = (const float*)d_in[4];
    const float* v_w    = (const float*)d_in[5];
    const float* v_b    = (const float*)d_in[6];
    const float* p_w    = (const float*)d_in[7];
    const float* p_b    = (const float*)d_in[8];
    const float* log_qw = (const float*)d_in[9];

    const size_t NM = (size_t)C_IN * N_SEQ;      // 1,059,840
    const size_t HN = (size_t)HEADS * N_SEQ;     // 33,120

    // pick key-split factor by available workspace
    int nz = 1;
    {
        auto need = [&](int zz) {
            return (3 * NM + (size_t)zz * HN * 2 + (size_t)zz * HN * 32) * sizeof(float);
        };
        if (ws_size >= need(4))      nz = 4;
        else if (ws_size >= need(2)) nz = 2;
        else                         nz = 1;
    }
    const int tiles_per_z = (NTILES + nz - 1) / nz;

    float* qkv      = (float*)d_ws;          // 3*NM
    float* pm       = qkv + 3 * NM;          // nz*HN
    float* pl       = pm + (size_t)nz * HN;  // nz*HN
    float* pacc     = pl + (size_t)nz * HN;  // nz*HN*32
    float* attn_out = qkv;                   // reuse q region after attention

    const int nblk = (N_SEQ + 255) / 256;    // 17

    qkv_kernel<<<dim3(nblk, 96), 256, 0, stream>>>(
        query, q_w, q_b, k_w, k_b, v_w, v_b, qkv);

    attn_kernel<<<dim3(nblk, HEADS, nz), 128, 0, stream>>>(
        qkv, log_qw, pm, pl, pacc, tiles_per_z);

    merge_kernel<<<dim3((int)((HN + 255) / 256)), 256, 0, stream>>>(
        pm, pl, pacc, attn_out, nz);

    proj_kernel<<<dim3(nblk, 32), 256, 0, stream>>>(
        attn_out, p_w, p_b, (float*)d_out);
}

// Round 4
// 240.707 us; speedup vs baseline: 2.9530x; 2.9530x over previous
//
#include <hip/hip_runtime.h>

#define N_SEQ 4140
#define NP    4160          // padded N (multiple of 32)
#define C_IN  256
#define HEADS 8
#define NT32  130           // ceil(4140/32) KV tiles / Q tiles
#define HN    (HEADS * N_SEQ)

typedef _Float16 f16x8 __attribute__((ext_vector_type(8)));
typedef float    f32x16 __attribute__((ext_vector_type(16)));

__device__ inline unsigned short f16b(float x) {
    union { _Float16 h; unsigned short s; } c;
    c.h = (_Float16)x;
    return c.s;
}
__device__ inline unsigned pack2h(float lo, float hi) {
    union { _Float16 h[2]; unsigned u; } c;
    c.h[0] = (_Float16)lo;      // element 0 = low 16 bits
    c.h[1] = (_Float16)hi;      // element 1 = high 16 bits
    return c.u;
}

// ---------------------------------------------------------------------------
// Pad init: lwp[0..4159] = log_qw or -1e30; zero V pad columns.
// ---------------------------------------------------------------------------
__global__ __launch_bounds__(256) void init_pad_kernel(
    const float* __restrict__ log_qw, float* __restrict__ lwp,
    unsigned short* __restrict__ vb)
{
    const int i = blockIdx.x * 256 + threadIdx.x;
    if (i < NP) lwp[i] = (i < N_SEQ) ? log_qw[i] : -1e30f;
    if (i < C_IN * (NP - N_SEQ)) {
        const int c = i / (NP - N_SEQ);
        const int col = N_SEQ + i % (NP - N_SEQ);
        vb[(size_t)c * NP + col] = 0;
    }
}

// ---------------------------------------------------------------------------
// QKV: f32 GEMM, f16 outputs. q,k -> [h][n][32] ; v -> [h*32+d][n]
// grid: (ceil(N/256), 96), blockIdx.y*8 selects 8 channels in [0,768)
// ---------------------------------------------------------------------------
__global__ __launch_bounds__(256) void qkv_kernel(
    const float* __restrict__ x,
    const float* __restrict__ q_w, const float* __restrict__ q_b,
    const float* __restrict__ k_w, const float* __restrict__ k_b,
    const float* __restrict__ v_w, const float* __restrict__ v_b,
    unsigned short* __restrict__ qo, unsigned short* __restrict__ ko,
    unsigned short* __restrict__ vo)
{
    const int n = blockIdx.x * 256 + threadIdx.x;
    const int cc0 = blockIdx.y * 8;
    const int mat = cc0 >> 8;          // 0=q, 1=k, 2=v
    const int row0 = cc0 & 255;
    const float* w; const float* b;
    if (mat == 0)      { w = q_w; b = q_b; }
    else if (mat == 1) { w = k_w; b = k_b; }
    else               { w = v_w; b = v_b; }
    if (n >= N_SEQ) return;

    float acc[8];
#pragma unroll
    for (int j = 0; j < 8; ++j) acc[j] = b[row0 + j];
    const float* wr = w + (size_t)row0 * C_IN;
    for (int c = 0; c < C_IN; ++c) {
        const float xv = x[(size_t)c * N_SEQ + n];
#pragma unroll
        for (int j = 0; j < 8; ++j)
            acc[j] = fmaf(wr[j * C_IN + c], xv, acc[j]);
    }

    if (mat < 2) {
        const int h = row0 >> 5;
        const int d0 = row0 & 31;
        union { unsigned short s[8]; uint4 q; } pk;
#pragma unroll
        for (int j = 0; j < 8; ++j) pk.s[j] = f16b(acc[j]);
        unsigned short* dst = (mat ? ko : qo) + ((size_t)(h * NP + n)) * 32 + d0;
        *(uint4*)dst = pk.q;
    } else {
#pragma unroll
        for (int j = 0; j < 8; ++j)
            vo[(size_t)(row0 + j) * NP + n] = f16b(acc[j]);
    }
}

// ---------------------------------------------------------------------------
// MFMA flash attention (f16). 4 independent waves per block; wave = one
// (head, q-tile of 32) job. Swapped QK^T: S[key][q] = mfma(A=K, B=Q^T);
// softmax lane-local (col = query); PV: O^T[d][q] = mfma(A=V^T, B=Pt).
// grid: (260, nz) x 256 threads.
// ---------------------------------------------------------------------------
__global__ __launch_bounds__(256) void attn_mfma_kernel(
    const unsigned short* __restrict__ qb, const unsigned short* __restrict__ kb,
    const unsigned short* __restrict__ vb, const float* __restrict__ lwp,
    float* __restrict__ pm, float* __restrict__ pl, float* __restrict__ pacc,
    int tiles_per_z)
{
    const int tid = threadIdx.x;
    const int wid = tid >> 6;
    const int lane = tid & 63;
    const int col = lane & 31;          // query column (QK) / d row (PV)
    const int hi = lane >> 5;
    const int job = blockIdx.x * 4 + wid;   // 0..1039
    const int h = job / NT32;
    const int qt = job % NT32;
    const int z = blockIdx.y;

    const int qrow = qt * 32 + col;
    // Q B-frags: B[k=d][col=q], lane reads 8 consecutive d at its q-row
    const unsigned short* qp = qb + ((size_t)(h * NP + qrow)) * 32 + hi * 8;
    const f16x8 qf0 = *(const f16x8*)(const void*)(qp);
    const f16x8 qf1 = *(const f16x8*)(const void*)(qp + 16);

    f32x16 o;
#pragma unroll
    for (int r = 0; r < 16; ++r) o[r] = 0.f;
    float m = -1e30f, lsum = 0.f;
    const float scale = 0.17677669529663687f;  // 1/sqrt(32)

    const int t0 = z * tiles_per_z;
    const int t1 = min(NT32, t0 + tiles_per_z);
    const unsigned short* kbase = kb + (size_t)h * NP * 32;
    const unsigned short* vrow  = vb + ((size_t)(h * 32 + col)) * NP;

    for (int t = t0; t < t1; ++t) {
        const int k0 = t * 32;
        // K A-frags: A[row=key][k=d]
        const unsigned short* kp = kbase + (size_t)(k0 + col) * 32 + hi * 8;
        const f16x8 ka0 = *(const f16x8*)(const void*)(kp);
        const f16x8 ka1 = *(const f16x8*)(const void*)(kp + 16);
        // V A-frags: A[row=d][k=key_local]
        const f16x8 va0 = *(const f16x8*)(const void*)(vrow + k0 + hi * 8);
        const f16x8 va1 = *(const f16x8*)(const void*)(vrow + k0 + 16 + hi * 8);
        // log quad weights for this lane's 16 key rows
        const float* lwb = lwp + k0 + 4 * hi;

        f32x16 s;
#pragma unroll
        for (int r = 0; r < 16; ++r) s[r] = 0.f;
        s = __builtin_amdgcn_mfma_f32_32x32x16_f16(ka0, qf0, s, 0, 0, 0);
        s = __builtin_amdgcn_mfma_f32_32x32x16_f16(ka1, qf1, s, 0, 0, 0);

        float p[16];
#pragma unroll
        for (int r = 0; r < 16; ++r)
            p[r] = fmaf(s[r], scale, lwb[(r & 3) + 8 * (r >> 2)]);

        float cmax = p[0];
#pragma unroll
        for (int r = 1; r < 16; ++r) cmax = fmaxf(cmax, p[r]);
        cmax = fmaxf(cmax, __shfl_xor(cmax, 32));
        const float mnew = fmaxf(m, cmax);
        const float esc = __expf(m - mnew);
        m = mnew;
        lsum *= esc;
#pragma unroll
        for (int r = 0; r < 16; ++r) o[r] *= esc;
        float psum = 0.f;
#pragma unroll
        for (int r = 0; r < 16; ++r) {
            p[r] = __expf(p[r] - mnew);
            psum += p[r];
        }
        lsum += psum;

        // pack P -> f16 B-frags (B[k=key][col=q]); partner exchange via shfl.
        // Lane (col,hi) holds P[key=(r&3)+8*(r>>2)+4*hi][col].
        union U { unsigned u[4]; f16x8 v; };
        const unsigned a0 = pack2h(p[0], p[1]),  b0 = pack2h(p[2], p[3]);
        const unsigned c0 = pack2h(p[4], p[5]),  d0 = pack2h(p[6], p[7]);
        const unsigned as = __shfl_xor(a0, 32), bs = __shfl_xor(b0, 32);
        const unsigned cs = __shfl_xor(c0, 32), ds = __shfl_xor(d0, 32);
        U pb0;
        pb0.u[0] = hi ? cs : a0;   // keys (8hi+0, 8hi+1)
        pb0.u[1] = hi ? ds : b0;   // keys (8hi+2, 8hi+3)
        pb0.u[2] = hi ? c0 : as;   // keys (8hi+4, 8hi+5)
        pb0.u[3] = hi ? d0 : bs;   // keys (8hi+6, 8hi+7)
        o = __builtin_amdgcn_mfma_f32_32x32x16_f16(va0, pb0.v, o, 0, 0, 0);

        const unsigned e0 = pack2h(p[8], p[9]),   f0 = pack2h(p[10], p[11]);
        const unsigned g0 = pack2h(p[12], p[13]), h0 = pack2h(p[14], p[15]);
        const unsigned es = __shfl_xor(e0, 32), fs = __shfl_xor(f0, 32);
        const unsigned gs = __shfl_xor(g0, 32), hs = __shfl_xor(h0, 32);
        U pb1;
        pb1.u[0] = hi ? gs : e0;   // keys 16+(8hi+0,8hi+1)
        pb1.u[1] = hi ? hs : f0;
        pb1.u[2] = hi ? g0 : es;
        pb1.u[3] = hi ? h0 : fs;
        o = __builtin_amdgcn_mfma_f32_32x32x16_f16(va1, pb1.v, o, 0, 0, 0);
    }

    lsum += __shfl_xor(lsum, 32);   // combine key-halves (partner lane)

    if (qrow < N_SEQ) {
        const size_t qi = (size_t)h * N_SEQ + qrow;
        if (hi == 0) {
            pm[(size_t)z * HN + qi] = m;
            pl[(size_t)z * HN + qi] = lsum;
        }
        float* pa = pacc + ((size_t)z * HN + qi) * 32;
#pragma unroll
        for (int r = 0; r < 16; ++r)
            pa[(r & 3) + 8 * (r >> 2) + 4 * hi] = o[r];
    }
}

// ---------------------------------------------------------------------------
// Merge key-split partials -> attn_out[c][n] (channel-major, f32)
// ---------------------------------------------------------------------------
__global__ __launch_bounds__(256) void merge_kernel(
    const float* __restrict__ pm, const float* __restrict__ pl,
    const float* __restrict__ pacc, float* __restrict__ attn_out, int nz)
{
    const int idx = blockIdx.x * 256 + threadIdx.x;
    if (idx >= HN) return;
    const int h = idx / N_SEQ;
    const int n = idx - h * N_SEQ;

    float mg = pm[idx];
    for (int zz = 1; zz < nz; ++zz) mg = fmaxf(mg, pm[(size_t)zz * HN + idx]);

    float lg = 0.f;
    float acc[32];
#pragma unroll
    for (int d = 0; d < 32; ++d) acc[d] = 0.f;
    for (int zz = 0; zz < nz; ++zz) {
        const float e = __expf(pm[(size_t)zz * HN + idx] - mg);
        lg += pl[(size_t)zz * HN + idx] * e;
        const float* pa = pacc + ((size_t)zz * HN + idx) * 32;
#pragma unroll
        for (int d = 0; d < 32; ++d) acc[d] = fmaf(pa[d], e, acc[d]);
    }
    const float inv = 1.0f / lg;
#pragma unroll
    for (int d = 0; d < 32; ++d)
        attn_out[(size_t)(h * 32 + d) * N_SEQ + n] = acc[d] * inv;
}

// ---------------------------------------------------------------------------
// Proj: out[k][n] = sum_c p_w[k][c] * attn_out[c][n] + p_b[k]  (f32)
// ---------------------------------------------------------------------------
__global__ __launch_bounds__(256) void proj_kernel(
    const float* __restrict__ x, const float* __restrict__ p_w,
    const float* __restrict__ p_b, float* __restrict__ out)
{
    const int n = blockIdx.x * 256 + threadIdx.x;
    const int row0 = blockIdx.y * 8;
    if (n >= N_SEQ) return;
    float acc[8];
#pragma unroll
    for (int j = 0; j < 8; ++j) acc[j] = p_b[row0 + j];
    const float* wr = p_w + (size_t)row0 * C_IN;
    for (int c = 0; c < C_IN; ++c) {
        const float xv = x[(size_t)c * N_SEQ + n];
#pragma unroll
        for (int j = 0; j < 8; ++j)
            acc[j] = fmaf(wr[j * C_IN + c], xv, acc[j]);
    }
#pragma unroll
    for (int j = 0; j < 8; ++j)
        out[(size_t)(row0 + j) * N_SEQ + n] = acc[j];
}

extern "C" void kernel_launch(void* const* d_in, const int* in_sizes, int n_in,
                              void* d_out, int out_size, void* d_ws, size_t ws_size,
                              hipStream_t stream) {
    const float* query  = (const float*)d_in[0];
    const float* q_w    = (const float*)d_in[1];
    const float* q_b    = (const float*)d_in[2];
    const float* k_w    = (const float*)d_in[3];
    const float* k_b    = (const float*)d_in[4];
    const float* v_w    = (const float*)d_in[5];
    const float* v_b    = (const float*)d_in[6];
    const float* p_w    = (const float*)d_in[7];
    const float* p_b    = (const float*)d_in[8];
    const float* log_qw = (const float*)d_in[9];

    const size_t BFELEM = (size_t)HEADS * NP * 32;   // 1,064,960 f16 per buf

    // ws layout
    unsigned short* qb = (unsigned short*)d_ws;
    unsigned short* kb = qb + BFELEM;
    unsigned short* vb = kb + BFELEM;
    float* lwp      = (float*)(vb + BFELEM);
    float* attn_out = lwp + NP;
    float* pm       = attn_out + (size_t)C_IN * N_SEQ;

    const size_t base_bytes = (size_t)((char*)pm - (char*)d_ws);
    const size_t per_z = (size_t)HN * 34 * sizeof(float);
    int nz = 1;
    if (ws_size >= base_bytes + 2 * per_z) nz = 2;
    const int tiles_per_z = (NT32 + nz - 1) / nz;

    float* pl   = pm + (size_t)nz * HN;
    float* pacc = pl + (size_t)nz * HN;

    const int nblk = (N_SEQ + 255) / 256;    // 17

    init_pad_kernel<<<dim3(20), 256, 0, stream>>>(log_qw, lwp, vb);

    qkv_kernel<<<dim3(nblk, 96), 256, 0, stream>>>(
        query, q_w, q_b, k_w, k_b, v_w, v_b, qb, kb, vb);

    attn_mfma_kernel<<<dim3(260, nz), 256, 0, stream>>>(
        qb, kb, vb, lwp, pm, pl, pacc, tiles_per_z);

    merge_kernel<<<dim3((HN + 255) / 256), 256, 0, stream>>>(
        pm, pl, pacc, attn_out, nz);

    proj_kernel<<<dim3(nblk, 32), 256, 0, stream>>>(
        attn_out, p_w, p_b, (float*)d_out);
}